// Round 6
// baseline (40900.601 us; speedup 1.0000x reference)
//
#include <hip/hip_runtime.h>
#include <hip/hip_fp16.h>

// B=1024, T=512, H=128, G=4H=512, IN=1
// 64 groups x 4 slices = 256 blocks x 512 thr; group = 16 batch rows; slice = 32 units.
#define TT 512

using f16   = _Float16;
using f16x8 = __attribute__((ext_vector_type(8))) _Float16;
using f32x4 = __attribute__((ext_vector_type(4))) float;

__device__ __forceinline__ float sigm(float x) {
    return __builtin_amdgcn_rcpf(1.0f + __builtin_amdgcn_exp2f(x * -1.44269504f));
}
__device__ __forceinline__ float tanh_(float x) {
    return 1.0f - 2.0f * __builtin_amdgcn_rcpf(1.0f + __builtin_amdgcn_exp2f(x * 2.88539008f));
}
// poison-safe spin: equality test (0xAAAAAAAA never equals step ids 1..512 or 777)
__device__ __forceinline__ void spin_eq(int* p, int want) {
    if (__hip_atomic_load(p, __ATOMIC_ACQUIRE, __HIP_MEMORY_SCOPE_AGENT) == want) return;
    while (__hip_atomic_load(p, __ATOMIC_RELAXED, __HIP_MEMORY_SCOPE_AGENT) != want)
        __builtin_amdgcn_s_sleep(1);
    (void)__hip_atomic_load(p, __ATOMIC_ACQUIRE, __HIP_MEMORY_SCOPE_AGENT);
}
__device__ __forceinline__ f16x8 cvt8(const float* p) {
    float4 a = ((const float4*)p)[0], b = ((const float4*)p)[1];
    return f16x8{(f16)a.x,(f16)a.y,(f16)a.z,(f16)a.w,
                 (f16)b.x,(f16)b.y,(f16)b.z,(f16)b.w};
}
// 4x4 transpose across a 4-lane quad (lane k = r&3) x 4 regs: out T_g = in[g-th lane's reg k]
__device__ __forceinline__ void xpose4(const f32x4 a, int r,
                                       float& T0, float& T1, float& T2, float& T3) {
    const bool kb0 = (r & 1) != 0, kb1 = (r & 2) != 0;
    float M0=a[0], M1=a[1], M2=a[2], M3=a[3];
    float s01 = __shfl_xor(M1, 1), s10 = __shfl_xor(M0, 1);
    float s23 = __shfl_xor(M3, 1), s32 = __shfl_xor(M2, 1);
    float A0 = kb0 ? s01 : M0;
    float A1 = kb0 ? M1  : s10;
    float A2 = kb0 ? s23 : M2;
    float A3 = kb0 ? M3  : s32;
    float u0 = __shfl_xor(A0, 2), u1 = __shfl_xor(A1, 2);
    float u2 = __shfl_xor(A2, 2), u3 = __shfl_xor(A3, 2);
    T0 = kb1 ? u2 : A0;
    T1 = kb1 ? u3 : A1;
    T2 = kb1 ? A2 : u0;
    T3 = kb1 ? A3 : u1;
}

// ws per group (stride 24576 B):
//   +0     h1G[2][16][128] f16   +8192  h2G[2][16][128] f16
//   +16384 f1[2][4][8] int       +16640 f2[2][4][8] int
//   +16896 fout[4] int           +16912 po[4][16] f32
// LDS (dynamic 98304 B -> forces 1 block/CU):
//   [0,8192)  h1L[2] (2 x 16 rows x 256B, chunk-swizzled)
//   [8192,16384) h2L[2]
//   [16384,...) red[128] f32
__global__ __launch_bounds__(512, 1) void lstm2_mc(
    const float* __restrict__ x,
    const float* __restrict__ Wih1,
    const float* __restrict__ Whh1,
    const float* __restrict__ bih1,
    const float* __restrict__ bhh1,
    const float* __restrict__ Wih2,
    const float* __restrict__ Whh2,
    const float* __restrict__ bih2,
    const float* __restrict__ bhh2,
    const float* __restrict__ Wl,
    const float* __restrict__ bl,
    float* __restrict__ out,
    char* __restrict__ ws)
{
    extern __shared__ char smem[];
    char*  const h1L = smem;                    // [2][4096]
    char*  const h2L = smem + 8192;             // [2][4096]
    float* const red = (float*)(smem + 16384);

    const int tid  = threadIdx.x;
    const int w    = tid >> 6;
    const int lane = tid & 63;
    const int r    = lane & 15;
    const int q    = lane >> 4;
    const int grp  = blockIdx.x >> 2;           // group 0..63
    const int s    = blockIdx.x & 3;            // slice 0..3

    char* const gb   = ws + (size_t)grp * 24576;
    f16*  const h1G  = (f16*)(gb);
    f16*  const h2G  = (f16*)(gb + 8192);
    int*  const f1   = (int*)(gb + 16384);      // [par*32 + sl*8 + wv]
    int*  const f2   = (int*)(gb + 16640);
    int*  const fout = (int*)(gb + 16896);
    float* const po  = (float*)(gb + 16912);    // [4][16]

    // cell ownership: row m (0..15), unit u (0..127)
    const int m  = q * 4 + (r & 3);
    const int u  = s * 32 + w * 4 + (r >> 2);
    const int row = grp * 16 + m;

    // per-cell constants
    float b1o[4], b2o[4], w1o[4];
    #pragma unroll
    for (int g = 0; g < 4; ++g) {
        int n = g * 128 + u;
        b1o[g] = bih1[n] + bhh1[n];
        b2o[g] = bih2[n] + bhh2[n];
        w1o[g] = Wih1[n];
    }
    const float wlv = Wl[u];
    const float bl0 = bl[0];

    // weight B-fragments, permuted columns: tile col r <-> gate (r&3) of unit u
    const int ncol = (r & 3) * 128 + u;
    f16x8 wb1[4], wbA[4], wbB[4];
    #pragma unroll
    for (int kt = 0; kt < 4; ++kt) {
        int k0 = kt * 32 + q * 8;
        wb1[kt] = cvt8(Whh1 + ncol * 128 + k0);   // layer-1 recurrent
        wbA[kt] = cvt8(Whh2 + ncol * 128 + k0);   // layer-2 recurrent
        wbB[kt] = cvt8(Wih2 + ncol * 128 + k0);   // layer-2 input (h1)
    }

    // A-fragment offsets (row = r, chunk-swizzled)
    int af[4];
    #pragma unroll
    for (int kt = 0; kt < 4; ++kt)
        af[kt] = r * 256 + ((kt * 64 + q * 16) ^ ((r & 7) << 4));

    // zero h1L[1] (bytes 4096..8192) and h2L[0] (8192..12288)
    *(f32x4*)(smem + 4096 + tid * 16) = f32x4{0.f, 0.f, 0.f, 0.f};

    float c1 = 0.f, c2 = 0.f, h2fin = 0.f;
    __syncthreads();

    for (int i = 0; i < TT; ++i) {
        const int p = i & 1, pp = p ^ 1;

        // wave1: spin siblings' h2(i-1) posts, issue stage loads (latency overlaps L1)
        f32x4 stg[4];
        if (w == 1 && i > 0) {
            if (lane < 32) spin_eq(&f2[pp * 32 + lane], i);
            #pragma unroll
            for (int t = 0; t < 4; ++t)
                stg[t] = *(const f32x4*)((const char*)h2G + pp * 4096 + t * 1024 + lane * 16);
        }

        // ---- layer 1: acc1 = h1(i-1) @ Whh1_cols ----
        f32x4 acc1 = {0.f, 0.f, 0.f, 0.f};
        #pragma unroll
        for (int kt = 0; kt < 4; ++kt) {
            f16x8 a = *(const f16x8*)(h1L + pp * 4096 + af[kt]);
            acc1 = __builtin_amdgcn_mfma_f32_16x16x32_f16(a, wb1[kt], acc1, 0, 0, 0);
        }
        const float xv = x[row * TT + i];

        // gate1: quad transpose -> this lane holds all 4 gates of (m, u)
        {
            float T0, T1, T2, T3;
            xpose4(acc1, r, T0, T1, T2, T3);
            float p0 = T0 + fmaf(xv, w1o[0], b1o[0]);
            float p1 = T1 + fmaf(xv, w1o[1], b1o[1]);
            float p2 = T2 + fmaf(xv, w1o[2], b1o[2]);
            float p3 = T3 + fmaf(xv, w1o[3], b1o[3]);
            float gi = sigm(p0), gf = sigm(p1), gg = tanh_(p2), go = sigm(p3);
            c1 = gf * c1 + gi * gg;
            float h1v = go * tanh_(c1);
            h1G[p * 2048 + m * 128 + u] = (f16)h1v;       // publish slice
        }
        if (lane == 0)
            __hip_atomic_store(&f1[p * 32 + s * 8 + w], i + 1,
                               __ATOMIC_RELEASE, __HIP_MEMORY_SCOPE_AGENT);

        // wave1: finish h2(i-1) stage into LDS (swizzled)
        if (w == 1 && i > 0) {
            #pragma unroll
            for (int t = 0; t < 4; ++t) {
                int byte = t * 1024 + lane * 16;
                int mr = byte >> 8, c16 = (byte >> 4) & 15;
                *(f32x4*)(h2L + p * 4096 + mr * 256 + ((c16 * 16) ^ ((mr & 7) << 4))) = stg[t];
            }
        }
        // wave0: spin all h1(i) posts (32 flags), stage h1(i) into LDS
        if (w == 0) {
            if (lane < 32) spin_eq(&f1[p * 32 + lane], i + 1);
            f32x4 sg[4];
            #pragma unroll
            for (int t = 0; t < 4; ++t)
                sg[t] = *(const f32x4*)((const char*)h1G + p * 4096 + t * 1024 + lane * 16);
            #pragma unroll
            for (int t = 0; t < 4; ++t) {
                int byte = t * 1024 + lane * 16;
                int mr = byte >> 8, c16 = (byte >> 4) & 15;
                *(f32x4*)(h1L + p * 4096 + mr * 256 + ((c16 * 16) ^ ((mr & 7) << 4))) = sg[t];
            }
        }

        __syncthreads();   // the ONE barrier per step

        // ---- layer 2: acc2 = h2(i-1) @ Whh2_cols + h1(i) @ Wih2_cols ----
        f32x4 acc2 = {0.f, 0.f, 0.f, 0.f};
        #pragma unroll
        for (int kt = 0; kt < 4; ++kt) {
            f16x8 a = *(const f16x8*)(h2L + p * 4096 + af[kt]);
            acc2 = __builtin_amdgcn_mfma_f32_16x16x32_f16(a, wbA[kt], acc2, 0, 0, 0);
        }
        #pragma unroll
        for (int kt = 0; kt < 4; ++kt) {
            f16x8 a = *(const f16x8*)(h1L + p * 4096 + af[kt]);
            acc2 = __builtin_amdgcn_mfma_f32_16x16x32_f16(a, wbB[kt], acc2, 0, 0, 0);
        }
        {
            float T0, T1, T2, T3;
            xpose4(acc2, r, T0, T1, T2, T3);
            float gi = sigm(T0 + b2o[0]);
            float gf = sigm(T1 + b2o[1]);
            float gg = tanh_(T2 + b2o[2]);
            float go = sigm(T3 + b2o[3]);
            c2 = gf * c2 + gi * gg;
            float h2v = go * tanh_(c2);
            h2fin = h2v;
            h2G[p * 2048 + m * 128 + u] = (f16)h2v;
        }
        if (lane == 0)
            __hip_atomic_store(&f2[p * 32 + s * 8 + w], i + 1,
                               __ATOMIC_RELEASE, __HIP_MEMORY_SCOPE_AGENT);
    }

    // ---- out[row] = sum_u h2(T-1)[row][u] * Wl[u] + bl ----
    float v = h2fin * wlv;
    v += __shfl_xor(v, 4);
    v += __shfl_xor(v, 8);                 // sum over (r>>2) within wave
    if ((r >> 2) == 0) red[w * 16 + m] = v;
    __syncthreads();
    if (tid < 16) {
        float a = 0.f;
        #pragma unroll
        for (int w8 = 0; w8 < 8; ++w8) a += red[w8 * 16 + tid];
        po[s * 16 + tid] = a;              // slice partial (global)
    }
    __syncthreads();                        // po stores drained
    if (tid == 0)
        __hip_atomic_store(&fout[s], 777, __ATOMIC_RELEASE, __HIP_MEMORY_SCOPE_AGENT);
    if (s == 0) {
        if (tid < 3) spin_eq(&fout[tid + 1], 777);
        __syncthreads();
        if (tid < 16) {
            float a = bl0;
            #pragma unroll
            for (int ss = 0; ss < 4; ++ss) a += po[ss * 16 + tid];
            out[grp * 16 + tid] = a;
        }
    }
}

extern "C" void kernel_launch(void* const* d_in, const int* in_sizes, int n_in,
                              void* d_out, int out_size, void* d_ws, size_t ws_size,
                              hipStream_t stream) {
    const float* x    = (const float*)d_in[0];
    const float* Wih1 = (const float*)d_in[1];
    const float* Whh1 = (const float*)d_in[2];
    const float* bih1 = (const float*)d_in[3];
    const float* bhh1 = (const float*)d_in[4];
    const float* Wih2 = (const float*)d_in[5];
    const float* Whh2 = (const float*)d_in[6];
    const float* bih2 = (const float*)d_in[7];
    const float* bhh2 = (const float*)d_in[8];
    const float* Wl   = (const float*)d_in[9];
    const float* bl   = (const float*)d_in[10];
    float* out = (float*)d_out;

    static constexpr size_t SMEM = 98304;   // forces 1 block/CU (160 KB pool)
    hipFuncSetAttribute(reinterpret_cast<const void*>(&lstm2_mc),
                        hipFuncAttributeMaxDynamicSharedMemorySize, (int)SMEM);

    lstm2_mc<<<dim3(256), dim3(512), SMEM, stream>>>(
        x, Wih1, Whh1, bih1, bhh1, Wih2, Whh2, bih2, bhh2, Wl, bl, out,
        (char*)d_ws);
}

// Round 7
// 1012.931 us; speedup vs baseline: 40.3785x; 40.3785x over previous
//
#include <hip/hip_runtime.h>
#include <hip/hip_fp16.h>

// B=1024, T=512, H=128, G=4H=512, IN=1
// 256 blocks x 512 thr; block owns 4 batch rows; wave w owns units [16w,16w+16).
// Software-pipelined: iter i does L1(i) and L2(i-1) in ONE phase, ONE barrier.
#define TT 512
#define RR 4

using f16   = _Float16;
using f16x8 = __attribute__((ext_vector_type(8))) _Float16;
using f32x4 = __attribute__((ext_vector_type(4))) float;

__device__ __forceinline__ float sigm(float x) {
    return __builtin_amdgcn_rcpf(1.0f + __builtin_amdgcn_exp2f(x * -1.44269504f));
}
__device__ __forceinline__ float tanh_(float x) {
    return 1.0f - 2.0f * __builtin_amdgcn_rcpf(1.0f + __builtin_amdgcn_exp2f(x * 2.88539008f));
}
__device__ __forceinline__ f16x8 cvt8(const float* p) {
    float4 a = ((const float4*)p)[0], b = ((const float4*)p)[1];
    return f16x8{(f16)a.x,(f16)a.y,(f16)a.z,(f16)a.w,
                 (f16)b.x,(f16)b.y,(f16)b.z,(f16)b.w};
}

// LDS (dynamic 151552 B):
//   [0,131072)        Whh2 f16, K-MAJOR: 16B chunk (kp,n) at (kp*512+n)*16,
//                     kp = k/8 (0..15), n = gate row (0..511). Conflict-free B reads.
//   [131072,133120)   h1 mailbox: 2 x [4 rows][256 B] f16, row-swizzled (^(m<<5))
//   [133120,135168)   h2 mailbox: same
//   [135168,151552)   per-wave strips: wave w at +w*2048 (L1 gates 0..1023, L2 1024..2047)
__global__ __launch_bounds__(512, 2) void lstm2_pipe(
    const float* __restrict__ x,
    const float* __restrict__ Wih1,
    const float* __restrict__ Whh1,
    const float* __restrict__ bih1,
    const float* __restrict__ bhh1,
    const float* __restrict__ Wih2,
    const float* __restrict__ Whh2,
    const float* __restrict__ bih2,
    const float* __restrict__ bhh2,
    const float* __restrict__ Wl,
    const float* __restrict__ bl,
    float* __restrict__ out)
{
    extern __shared__ char smem[];
    char* const w2hL   = smem;
    char* const h1m    = smem + 131072;
    char* const h2m    = smem + 133120;
    char* const strips = smem + 135168;

    const int tid  = threadIdx.x;
    const int w    = tid >> 6;
    const int lane = tid & 63;
    const int r    = lane & 15;
    const int q    = lane >> 4;
    const int rowbase = blockIdx.x * RR;

    // zero both mailboxes (4096 B contiguous)
    *(float2*)(smem + 131072 + tid * 8) = float2{0.f, 0.f};

    // stage Whh2 -> LDS f16, K-major chunks
    for (int it = 0; it < 16; ++it) {
        int pp = tid + it * 512;       // chunk id 0..8191
        int kp = pp >> 9;              // k-chunk 0..15
        int n  = pp & 511;             // gate row
        *(f16x8*)(w2hL + (kp * 512 + n) * 16) = cvt8(Whh2 + n * 128 + kp * 8);
    }

    // per-cell constants: this lane owns cell (m=q, u=16w+r)
    float b1o[4], b2o[4], w1o[4];
    #pragma unroll
    for (int g = 0; g < 4; ++g) {
        int n = g * 128 + w * 16 + r;
        b1o[g] = bih1[n] + bhh1[n];
        b2o[g] = bih2[n] + bhh2[n];
        w1o[g] = Wih1[n];
    }
    const float wlv = Wl[w * 16 + r];
    const float bl0 = bl[0];

    // register B-fragments: Whh1 (L1) + Wih2 (L2 input term). 128 VGPRs.
    f16x8 wr1[4][4], w2i[4][4];
    #pragma unroll
    for (int g = 0; g < 4; ++g) {
        int n = g * 128 + w * 16 + r;
        #pragma unroll
        for (int kt = 0; kt < 4; ++kt) {
            int k0 = kt * 32 + q * 8;
            wr1[g][kt] = cvt8(Whh1 + n * 128 + k0);
            w2i[g][kt] = cvt8(Wih2 + n * 128 + k0);
        }
    }

    // A-fragment offsets in a 1KB mailbox buffer: row m=r&3, 16B chunk ^(m<<5)
    int afm[4];
    #pragma unroll
    for (int kt = 0; kt < 4; ++kt)
        afm[kt] = (r & 3) * 256 + ((kt * 64 + q * 16) ^ ((r & 3) << 5));
    const bool rlow = (r < 4);
    const f16x8 zf = f16x8{0,0,0,0,0,0,0,0};
    // paired h-write (even r lanes): b32 at row q, units (16w+r, +1), swizzled
    const int hwb = q * 256 + (((w << 5) + 2 * r) ^ (q << 5));
    char* const strip = strips + w * 2048;

    float c1 = 0.f, c2 = 0.f, h2fin = 0.f;

    __syncthreads();

    for (int i = 0; i <= TT; ++i) {
        const int p = i & 1, pp = p ^ 1;
        const bool doL1 = (i < TT), doL2 = (i > 0);

        // A-fragments: h1(i-1) shared by L1 and L2-input term; h2(i-2) for L2
        f16x8 a1[4], ah2[4];
        #pragma unroll
        for (int kt = 0; kt < 4; ++kt) {
            f16x8 v = *(const f16x8*)(h1m + pp * 1024 + afm[kt]);
            a1[kt] = rlow ? v : zf;
        }
        if (doL2) {
            #pragma unroll
            for (int kt = 0; kt < 4; ++kt) {
                f16x8 v = *(const f16x8*)(h2m + p * 1024 + afm[kt]);
                ah2[kt] = rlow ? v : zf;
            }
        }
        const float xv = doL1 ? x[(rowbase + q) * TT + i] : 0.f;

        // ---- all MFMAs for this iter (independent acc chains) ----
        f32x4 acc1[4] = {{0,0,0,0},{0,0,0,0},{0,0,0,0},{0,0,0,0}};
        f32x4 acc2[4] = {{0,0,0,0},{0,0,0,0},{0,0,0,0},{0,0,0,0}};
        if (doL1) {
            #pragma unroll
            for (int g = 0; g < 4; ++g)
                #pragma unroll
                for (int kt = 0; kt < 4; ++kt)
                    acc1[g] = __builtin_amdgcn_mfma_f32_16x16x32_f16(
                        a1[kt], wr1[g][kt], acc1[g], 0, 0, 0);
        }
        if (doL2) {
            #pragma unroll
            for (int g = 0; g < 4; ++g) {
                #pragma unroll
                for (int kt = 0; kt < 4; ++kt)
                    acc2[g] = __builtin_amdgcn_mfma_f32_16x16x32_f16(
                        a1[kt], w2i[g][kt], acc2[g], 0, 0, 0);
                #pragma unroll
                for (int kt = 0; kt < 4; ++kt) {
                    f16x8 bf = *(const f16x8*)(w2hL +
                        ((kt * 4 + q) * 512 + g * 128 + w * 16 + r) * 16);
                    acc2[g] = __builtin_amdgcn_mfma_f32_16x16x32_f16(
                        ah2[kt], bf, acc2[g], 0, 0, 0);
                }
            }
        }

        // ---- strip redistribute (per-wave private; intra-wave visibility) ----
        if (q == 0) {
            if (doL1) {
                #pragma unroll
                for (int g = 0; g < 4; ++g)
                    *(f32x4*)(strip + g * 256 + r * 16) = acc1[g];
            }
            if (doL2) {
                #pragma unroll
                for (int g = 0; g < 4; ++g)
                    *(f32x4*)(strip + 1024 + g * 256 + r * 16) = acc2[g];
            }
        }

        // ---- gate math: 2 independent cells per lane ----
        if (doL1) {
            float pg[4];
            #pragma unroll
            for (int g = 0; g < 4; ++g)
                pg[g] = ((const float*)(strip + g * 256 + r * 16))[q]
                        + fmaf(xv, w1o[g], b1o[g]);
            float gi = sigm(pg[0]), gf = sigm(pg[1]);
            float gg = tanh_(pg[2]), go = sigm(pg[3]);
            c1 = gf * c1 + gi * gg;
            float hv = go * tanh_(c1);
            float hn = __shfl_xor(hv, 1);
            if ((r & 1) == 0) {
                union { f16 h[2]; unsigned u; } pk;
                pk.h[0] = (f16)hv; pk.h[1] = (f16)hn;
                *(unsigned*)(h1m + p * 1024 + hwb) = pk.u;
            }
        }
        if (doL2) {
            float pg[4];
            #pragma unroll
            for (int g = 0; g < 4; ++g)
                pg[g] = ((const float*)(strip + 1024 + g * 256 + r * 16))[q] + b2o[g];
            float gi = sigm(pg[0]), gf = sigm(pg[1]);
            float gg = tanh_(pg[2]), go = sigm(pg[3]);
            c2 = gf * c2 + gi * gg;
            float hv = go * tanh_(c2);
            h2fin = hv;
            float hn = __shfl_xor(hv, 1);
            if ((r & 1) == 0) {
                union { f16 h[2]; unsigned u; } pk;
                pk.h[0] = (f16)hv; pk.h[1] = (f16)hn;
                *(unsigned*)(h2m + pp * 1024 + hwb) = pk.u;
            }
        }

        __syncthreads();   // the ONE barrier per iteration
    }

    // ---- out[m] = sum_u h2(T-1)[m][u] * Wl[u] + bl ; lane owns (m=q, u=16w+r) ----
    float v = h2fin * wlv;
    v += __shfl_xor(v, 1);
    v += __shfl_xor(v, 2);
    v += __shfl_xor(v, 4);
    v += __shfl_xor(v, 8);                 // lane r==0 per q: wave partial
    float* red = (float*)strips;           // reuse strips (post-loop)
    if (r == 0) red[q * 8 + w] = v;
    __syncthreads();
    if (tid < RR) {
        float a = bl0;
        #pragma unroll
        for (int s = 0; s < 8; ++s) a += red[tid * 8 + s];
        out[rowbase + tid] = a;
    }
}

extern "C" void kernel_launch(void* const* d_in, const int* in_sizes, int n_in,
                              void* d_out, int out_size, void* d_ws, size_t ws_size,
                              hipStream_t stream) {
    const float* x    = (const float*)d_in[0];
    const float* Wih1 = (const float*)d_in[1];
    const float* Whh1 = (const float*)d_in[2];
    const float* bih1 = (const float*)d_in[3];
    const float* bhh1 = (const float*)d_in[4];
    const float* Wih2 = (const float*)d_in[5];
    const float* Whh2 = (const float*)d_in[6];
    const float* bih2 = (const float*)d_in[7];
    const float* bhh2 = (const float*)d_in[8];
    const float* Wl   = (const float*)d_in[9];
    const float* bl   = (const float*)d_in[10];
    float* out = (float*)d_out;

    static constexpr size_t SMEM = 151552;
    hipFuncSetAttribute(reinterpret_cast<const void*>(&lstm2_pipe),
                        hipFuncAttributeMaxDynamicSharedMemorySize, (int)SMEM);

    lstm2_pipe<<<dim3(256), dim3(512), SMEM, stream>>>(
        x, Wih1, Whh1, bih1, bhh1, Wih2, Whh2, bih2, bhh2, Wl, bl, out);
}